// Round 4
// baseline (334.978 us; speedup 1.0000x reference)
//
#include <hip/hip_runtime.h>
#include <hip/hip_bf16.h>

typedef __attribute__((ext_vector_type(4))) float f32x4;
typedef __attribute__((ext_vector_type(8))) short s16x8;
typedef __attribute__((ext_vector_type(4))) short s16x4;

#define NROWS 4096
#define DMODEL 256
#define NHEAD 8
#define HDIM 32
#define PSTRIDE 72     // halfwords per P-scratch row: 144 B, 16B-aligned
#define OSTRIDE 20     // f32 per sO row
#define M2C 24.0f      // fixed softmax max (log2 domain); |scores| < ~8

__device__ __forceinline__ short bf16r(float f) {
    union { float f; unsigned u; } v; v.f = f;
    unsigned r = v.u + 0x7fffu + ((v.u >> 16) & 1u);  // RNE
    return (short)(r >> 16);
}

__device__ __forceinline__ float fexp2(float x) {
    float r;
    asm("v_exp_f32 %0, %1" : "=v"(r) : "v"(x));   // guaranteed single trans op
    return r;
}

__device__ __forceinline__ unsigned pk_bf16(float a, float b) {
#if __has_builtin(__builtin_amdgcn_cvt_pk_bf16_f32)
    typedef __bf16 bf2 __attribute__((ext_vector_type(2)));
    union { bf2 h; unsigned u; } c;
    c.h = __builtin_amdgcn_cvt_pk_bf16_f32(a, b);
    return c.u;
#else
    return (unsigned)(unsigned short)bf16r(a) | ((unsigned)(unsigned short)bf16r(b) << 16);
#endif
}

__device__ __forceinline__ s16x8 pack8(float4 a, float4 b) {
    s16x8 r;
    r[0] = bf16r(a.x); r[1] = bf16r(a.y); r[2] = bf16r(a.z); r[3] = bf16r(a.w);
    r[4] = bf16r(b.x); r[5] = bf16r(b.y); r[6] = bf16r(b.z); r[7] = bf16r(b.w);
    return r;
}

// ---------------------------------------------------------------------------
// adj (4096x4096 int32) -> packed bitmask (4096 x 128 u32), diag OR'd in.
__global__ __launch_bounds__(256) void pack_adj(const int* __restrict__ adj,
                                                unsigned* __restrict__ mask) {
    const int gw   = (blockIdx.x * 256 + threadIdx.x) >> 6;
    const int lane = threadIdx.x & 63;
    const int row  = gw >> 6;
    const int chunk = gw & 63;
    const int c = chunk * 64 + lane;
    int a = adj[(size_t)row * NROWS + c];
    unsigned long long m = __ballot(a > 0 || c == row);
    if (lane == 0)      mask[row * 128 + chunk * 2]     = (unsigned)m;
    else if (lane == 1) mask[row * 128 + chunk * 2 + 1] = (unsigned)(m >> 32);
}

// ---------------------------------------------------------------------------
// Convert all 6 weight matrices to bf16 once (concatenated: Wq,Wk,Wv,Wo,W1,W2)
__global__ __launch_bounds__(256) void prep_w(const float* __restrict__ Wq,
                                              const float* __restrict__ Wk,
                                              const float* __restrict__ Wv,
                                              const float* __restrict__ Wo,
                                              const float* __restrict__ W1,
                                              const float* __restrict__ W2,
                                              short* __restrict__ out) {
    int i = (blockIdx.x * 256 + threadIdx.x) * 8;  // total 524288 floats
    const float* src; int off;
    if (i < 262144) {
        const float* ws[4] = {Wq, Wk, Wv, Wo};
        src = ws[i >> 16]; off = i & 65535;
    } else if (i < 393216) { src = W1; off = i - 262144; }
    else                   { src = W2; off = i - 393216; }
    float4 a = *(const float4*)(src + off);
    float4 b = *(const float4*)(src + off + 4);
    *(s16x8*)(out + i) = pack8(a, b);
}

// ---------------------------------------------------------------------------
// QKV projection: per-wave 16x16 tile for 4 waves/SIMD. Q gets scale*log2e
// folded in. Layouts: Qb[n][d], Kb[h][key][hd], Vtb[h][hd][key].
__global__ __launch_bounds__(256) void qkv_kernel(const float* __restrict__ X,
                                                  const short* __restrict__ Wb,
                                                  const float* __restrict__ bq,
                                                  const float* __restrict__ bk,
                                                  const float* __restrict__ bv,
                                                  short* __restrict__ Qb,
                                                  short* __restrict__ Kb,
                                                  short* __restrict__ Vtb) {
    const int z = blockIdx.z;
    const short* W = Wb + (size_t)z * 65536;
    const float* bias = (z == 0) ? bq : (z == 1 ? bk : bv);
    const int tid = threadIdx.x;
    const int wv = tid >> 6, lane = tid & 63;
    const int quad = lane >> 4, col = lane & 15;
    const int n0 = (blockIdx.x * 4 + wv) * 16;
    const int o0 = blockIdx.y * 16;
    const float QSC = 0.25505653437397888f;  // log2e / sqrt(32)

    f32x4 acc = {0.f, 0.f, 0.f, 0.f};
    const float* ap = X + (size_t)(n0 + col) * DMODEL + quad * 8;
    const short* wp = W + (size_t)(o0 + col) * DMODEL + quad * 8;
#pragma unroll
    for (int k0 = 0; k0 < DMODEL; k0 += 32) {
        float4 a0 = *(const float4*)(ap + k0);
        float4 a1 = *(const float4*)(ap + k0 + 4);
        s16x8 af = pack8(a0, a1);
        s16x8 bf = *(const s16x8*)(wp + k0);
        acc = __builtin_amdgcn_mfma_f32_16x16x32_bf16(af, bf, acc, 0, 0, 0);
    }
    const int o = o0 + col;
    float bvv = bias[o];
#pragma unroll
    for (int r = 0; r < 4; ++r) {
        int n = n0 + quad * 4 + r;
        float v = acc[r] + bvv;
        if (z == 0)      Qb[(size_t)n * DMODEL + o] = bf16r(v * QSC);
        else if (z == 1) Kb[(size_t)(o >> 5) * NROWS * HDIM + (size_t)n * HDIM + (o & 31)] = bf16r(v);
        else             Vtb[(size_t)o * NROWS + n] = bf16r(v);
    }
}

// ---------------------------------------------------------------------------
// Flash attention, S^T orientation, fixed-M softmax (no running max).
// Block = (16 q, 1 head), 4 waves; wave w owns keys [w*1024, w*1024+1024).
// Grid 2048 blocks -> 8192 waves -> 8 waves/SIMD; LDS ~19.7 KB -> 8 blocks/CU.
__global__ __launch_bounds__(256) void attn_kernel(const short* __restrict__ Qb,
                                                   const short* __restrict__ Kb,
                                                   const short* __restrict__ Vtb,
                                                   const unsigned* __restrict__ mask,
                                                   short* __restrict__ Om) {
    __shared__ short sP[4][16 * PSTRIDE];      //  9216 B
    __shared__ float sO[4][32][OSTRIDE];       // 10240 B
    __shared__ float sl[4][16];                //   256 B

    const int tid = threadIdx.x;
    const int wv = tid >> 6, lane = tid & 63;
    const int quad = lane >> 4, col = lane & 15;
    const int h = blockIdx.x & 7;
    const int q0 = (blockIdx.x >> 3) * 16;
    const int kw = wv * 1024;

    // Q as B-operand: B[k=quad*8+j=hd][n=col=q]
    s16x8 qf = *(const s16x8*)(Qb + (size_t)(q0 + col) * DMODEL + h * HDIM + quad * 8);

    const short* kp  = Kb + (size_t)h * NROWS * HDIM + (size_t)(kw + col) * HDIM + quad * 8;
    const short* vp0 = Vtb + (size_t)(h * HDIM + col) * NROWS + kw + quad * 8;
    const short* vp1 = vp0 + (size_t)16 * NROWS;
    const unsigned* mp = mask + (size_t)(q0 + col) * 128 + (kw >> 5);
    short* pb = &sP[wv][0];

    f32x4 acc0 = {0.f, 0.f, 0.f, 0.f}, acc1 = {0.f, 0.f, 0.f, 0.f};
    float rs = 0.f;
    const f32x4 cinit = {-M2C, -M2C, -M2C, -M2C};

    for (int it = 0; it < 16; ++it) {
        s16x8 kf0 = *(const s16x8*)(kp);
        s16x8 kf1 = *(const s16x8*)(kp + 16 * HDIM);
        s16x8 kf2 = *(const s16x8*)(kp + 32 * HDIM);
        s16x8 kf3 = *(const s16x8*)(kp + 48 * HDIM);
        s16x8 vf00 = *(const s16x8*)(vp0);
        s16x8 vf01 = *(const s16x8*)(vp0 + 32);
        s16x8 vf10 = *(const s16x8*)(vp1);
        s16x8 vf11 = *(const s16x8*)(vp1 + 32);
        uint2 w = *(const uint2*)mp;     // keys 0-31, 32-63 of this tile
        kp += 64 * HDIM; vp0 += 64; vp1 += 64; mp += 2;

        unsigned wlo = w.x >> (quad * 4);
        unsigned whi = w.y >> (quad * 4);

        // S^T tiles with C = -M2C preloaded
        f32x4 st[4];
        st[0] = __builtin_amdgcn_mfma_f32_16x16x32_bf16(kf0, qf, cinit, 0, 0, 0);
        st[1] = __builtin_amdgcn_mfma_f32_16x16x32_bf16(kf1, qf, cinit, 0, 0, 0);
        st[2] = __builtin_amdgcn_mfma_f32_16x16x32_bf16(kf2, qf, cinit, 0, 0, 0);
        st[3] = __builtin_amdgcn_mfma_f32_16x16x32_bf16(kf3, qf, cinit, 0, 0, 0);

        float p[4][4];
        float r0 = 0.f;
#pragma unroll
        for (int t = 0; t < 4; ++t) {
            unsigned wm = (t < 2) ? wlo : whi;
#pragma unroll
            for (int r = 0; r < 4; ++r) {
                float e = fexp2(st[t][r]);
                bool ok = (wm & (1u << ((t & 1) * 16 + r))) != 0u;
                p[t][r] = ok ? e : 0.f;
                r0 += p[t][r];
            }
        }
        rs += r0;

        // P (C-layout) -> per-wave LDS scratch -> B-layout (same-wave, no barrier)
#pragma unroll
        for (int t = 0; t < 4; ++t) {
            uint2 pr;
            pr.x = pk_bf16(p[t][0], p[t][1]);
            pr.y = pk_bf16(p[t][2], p[t][3]);
            *(uint2*)(pb + col * PSTRIDE + t * 16 + quad * 4) = pr;
        }
        s16x8 pb0 = *(const s16x8*)(pb + col * PSTRIDE + quad * 8);
        s16x8 pb1 = *(const s16x8*)(pb + col * PSTRIDE + 32 + quad * 8);

        // O^T[hd][q] += V^T frag (A) x P frag (B)
        acc0 = __builtin_amdgcn_mfma_f32_16x16x32_bf16(vf00, pb0, acc0, 0, 0, 0);
        acc0 = __builtin_amdgcn_mfma_f32_16x16x32_bf16(vf01, pb1, acc0, 0, 0, 0);
        acc1 = __builtin_amdgcn_mfma_f32_16x16x32_bf16(vf10, pb0, acc1, 0, 0, 0);
        acc1 = __builtin_amdgcn_mfma_f32_16x16x32_bf16(vf11, pb1, acc1, 0, 0, 0);
    }

    // partition partials to LDS (plain sums; fixed M -> no rescale)
    float r = rs;
    r += __shfl_xor(r, 16, 64);
    r += __shfl_xor(r, 32, 64);
    if (lane < 16) sl[wv][col] = r;
#pragma unroll
    for (int rr = 0; rr < 4; ++rr) {
        sO[wv][quad * 4 + rr][col]      = acc0[rr];
        sO[wv][16 + quad * 4 + rr][col] = acc1[rr];
    }
    __syncthreads();

    // merge 4 key-partitions; thread -> (q = tid>>4, hd pair = (tid&15)*2)
    const int q = tid >> 4, dp = (tid & 15) * 2;
    float l = sl[0][q] + sl[1][q] + sl[2][q] + sl[3][q];
    float inv = 1.f / l;  // diagonal always allowed -> l > 0
    float o0v = (sO[0][dp][q] + sO[1][dp][q] + sO[2][dp][q] + sO[3][dp][q]) * inv;
    float o1v = (sO[0][dp + 1][q] + sO[1][dp + 1][q] + sO[2][dp + 1][q] + sO[3][dp + 1][q]) * inv;
    *(unsigned*)(Om + (size_t)(q0 + q) * DMODEL + h * HDIM + dp) = pk_bf16(o0v, o1v);
}

// ---------------------------------------------------------------------------
// bf16-in GEMM, per-wave 16x16 tile (high wave parallelism), compile-time K.
template<int K, bool RELU, bool B16OUT>
__global__ __launch_bounds__(256) void gemm_t(const short* __restrict__ A,
                                              const short* __restrict__ W,
                                              const float* __restrict__ bias,
                                              float* __restrict__ Cf,
                                              short* __restrict__ Cb,
                                              int Ocols) {
    const int tid = threadIdx.x;
    const int wv = tid >> 6, lane = tid & 63;
    const int quad = lane >> 4, col = lane & 15;
    const int n0 = (blockIdx.x * 4 + wv) * 16;
    const int o0 = blockIdx.y * 16;
    f32x4 acc = {0.f, 0.f, 0.f, 0.f};
    const short* ap = A + (size_t)(n0 + col) * K + quad * 8;
    const short* wp = W + (size_t)(o0 + col) * K + quad * 8;
#pragma unroll
    for (int k0 = 0; k0 < K; k0 += 32) {
        s16x8 af = *(const s16x8*)(ap + k0);
        s16x8 bf = *(const s16x8*)(wp + k0);
        acc = __builtin_amdgcn_mfma_f32_16x16x32_bf16(af, bf, acc, 0, 0, 0);
    }
    const int o = o0 + col;
    float bvv = bias[o];
#pragma unroll
    for (int r = 0; r < 4; ++r) {
        int n = n0 + quad * 4 + r;
        float v = acc[r] + bvv;
        if (RELU) v = fmaxf(v, 0.f);
        if (B16OUT) Cb[(size_t)n * Ocols + o] = bf16r(v);
        else        Cf[(size_t)n * Ocols + o] = v;
    }
}

// ---------------------------------------------------------------------------
// y = LN(a+b)*g + beta; writes f32 Y and optional bf16 Yb.
__global__ __launch_bounds__(256) void ln_kernel(const float* __restrict__ Xa,
                                                 const float* __restrict__ Xb,
                                                 const float* __restrict__ g,
                                                 const float* __restrict__ be,
                                                 float* __restrict__ Y,
                                                 short* __restrict__ Yb) {
    const int wv = threadIdx.x >> 6, lane = threadIdx.x & 63;
    const int row = blockIdx.x * 4 + wv;
    const float4 av = *(const float4*)(Xa + (size_t)row * DMODEL + lane * 4);
    const float4 bv = *(const float4*)(Xb + (size_t)row * DMODEL + lane * 4);
    float v0 = av.x + bv.x, v1 = av.y + bv.y, v2 = av.z + bv.z, v3 = av.w + bv.w;
    float s = v0 + v1 + v2 + v3;
#pragma unroll
    for (int m = 1; m < 64; m <<= 1) s += __shfl_xor(s, m, 64);
    float mean = s * (1.f / 256.f);
    float d0 = v0 - mean, d1 = v1 - mean, d2 = v2 - mean, d3 = v3 - mean;
    float q = d0 * d0 + d1 * d1 + d2 * d2 + d3 * d3;
#pragma unroll
    for (int m = 1; m < 64; m <<= 1) q += __shfl_xor(q, m, 64);
    float rstd = rsqrtf(q * (1.f / 256.f) + 1e-5f);
    const float4 gv  = *(const float4*)(g + lane * 4);
    const float4 bev = *(const float4*)(be + lane * 4);
    float4 y;
    y.x = d0 * rstd * gv.x + bev.x;
    y.y = d1 * rstd * gv.y + bev.y;
    y.z = d2 * rstd * gv.z + bev.z;
    y.w = d3 * rstd * gv.w + bev.w;
    *(float4*)(Y + (size_t)row * DMODEL + lane * 4) = y;
    if (Yb) {
        uint2 yb;
        yb.x = pk_bf16(y.x, y.y);
        yb.y = pk_bf16(y.z, y.w);
        *(uint2*)(Yb + (size_t)row * DMODEL + lane * 4) = yb;
    }
}

// ---------------------------------------------------------------------------
extern "C" void kernel_launch(void* const* d_in, const int* in_sizes, int n_in,
                              void* d_out, int out_size, void* d_ws, size_t ws_size,
                              hipStream_t stream) {
    const float* x   = (const float*)d_in[0];
    const int*   adj = (const int*)d_in[1];
    const float* Wq  = (const float*)d_in[2];
    const float* Wk  = (const float*)d_in[3];
    const float* Wv  = (const float*)d_in[4];
    const float* bq  = (const float*)d_in[5];
    const float* bk  = (const float*)d_in[6];
    const float* bv  = (const float*)d_in[7];
    const float* Wo  = (const float*)d_in[8];
    const float* bo  = (const float*)d_in[9];
    const float* g1  = (const float*)d_in[10];
    const float* be1 = (const float*)d_in[11];
    const float* W1  = (const float*)d_in[12];
    const float* b1  = (const float*)d_in[13];
    const float* W2  = (const float*)d_in[14];
    const float* b2  = (const float*)d_in[15];
    const float* g2  = (const float*)d_in[16];
    const float* be2 = (const float*)d_in[17];
    float* out = (float*)d_out;

    const size_t NM = (size_t)NROWS * DMODEL;
    char* p = (char*)d_ws;
    unsigned* mask = (unsigned*)p; p += (size_t)NROWS * 128 * 4;  // 2 MB
    short* Wb   = (short*)p;       p += (size_t)524288 * 2;       // 1 MB
    short* Qb   = (short*)p;       p += NM * 2;                   // 2 MB
    short* Kb   = (short*)p;       p += NM * 2;                   // 2 MB
    short* Vtb  = (short*)p;       p += NM * 2;                   // 2 MB
    short* Omb  = (short*)p;       p += NM * 2;                   // 2 MB
    float* hbuf = (float*)p;       p += NM * 4;                   // 4 MB
    float* y1   = (float*)p;       p += NM * 4;                   // 4 MB
    short* y1b  = (short*)p;       p += NM * 2;                   // 2 MB
    short* rbuf = (short*)p;       p += (size_t)NROWS * 512 * 2;  // 4 MB
    float* t2   = (float*)p;       p += NM * 4;                   // 4 MB

    pack_adj<<<dim3(NROWS * 64 / 4), dim3(256), 0, stream>>>(adj, mask);
    prep_w<<<dim3(256), dim3(256), 0, stream>>>(Wq, Wk, Wv, Wo, W1, W2, Wb);
    qkv_kernel<<<dim3(64, 16, 3), dim3(256), 0, stream>>>(x, Wb, bq, bk, bv, Qb, Kb, Vtb);
    attn_kernel<<<dim3(2048), dim3(256), 0, stream>>>(Qb, Kb, Vtb, mask, Omb);
    gemm_t<256, false, false><<<dim3(64, 16), dim3(256), 0, stream>>>(Omb, Wb + 196608, bo, hbuf, nullptr, 256);
    ln_kernel<<<dim3(1024), dim3(256), 0, stream>>>(x, hbuf, g1, be1, y1, y1b);
    gemm_t<256, true, true><<<dim3(64, 32), dim3(256), 0, stream>>>(y1b, Wb + 262144, b1, nullptr, rbuf, 512);
    gemm_t<512, false, false><<<dim3(64, 16), dim3(256), 0, stream>>>(rbuf, Wb + 393216, b2, t2, nullptr, 256);
    ln_kernel<<<dim3(1024), dim3(256), 0, stream>>>(y1, t2, g2, be2, out, nullptr);
}

// Round 5
// 299.062 us; speedup vs baseline: 1.1201x; 1.1201x over previous
//
#include <hip/hip_runtime.h>
#include <hip/hip_bf16.h>

typedef __attribute__((ext_vector_type(4))) float f32x4;
typedef __attribute__((ext_vector_type(8))) short s16x8;
typedef __attribute__((ext_vector_type(4))) short s16x4;

#define NROWS 4096
#define DMODEL 256
#define NHEAD 8
#define HDIM 32
#define PSTRIDE 72     // halfwords per P-scratch row: 144 B, 16B-aligned
#define OSTRIDE 33     // f32 per sO row (32 q + 1 pad): <=2-way banks
#define M2C 24.0f      // fixed softmax max (log2 domain)

__device__ __forceinline__ short bf16r(float f) {
    union { float f; unsigned u; } v; v.f = f;
    unsigned r = v.u + 0x7fffu + ((v.u >> 16) & 1u);  // RNE
    return (short)(r >> 16);
}

__device__ __forceinline__ float fexp2(float x) {
    float r;
    asm("v_exp_f32 %0, %1" : "=v"(r) : "v"(x));
    return r;
}

__device__ __forceinline__ unsigned pk_bf16(float a, float b) {
#if __has_builtin(__builtin_amdgcn_cvt_pk_bf16_f32)
    typedef __bf16 bf2 __attribute__((ext_vector_type(2)));
    union { bf2 h; unsigned u; } c;
    c.h = __builtin_amdgcn_cvt_pk_bf16_f32(a, b);
    return c.u;
#else
    return (unsigned)(unsigned short)bf16r(a) | ((unsigned)(unsigned short)bf16r(b) << 16);
#endif
}

__device__ __forceinline__ s16x8 pack8(float4 a, float4 b) {
    s16x8 r;
    r[0] = bf16r(a.x); r[1] = bf16r(a.y); r[2] = bf16r(a.z); r[3] = bf16r(a.w);
    r[4] = bf16r(b.x); r[5] = bf16r(b.y); r[6] = bf16r(b.z); r[7] = bf16r(b.w);
    return r;
}

// ---------------------------------------------------------------------------
// Fused: blocks [0,65536): adj -> bitmask (diag OR'd).  blocks [65536,65792):
// pack 6 weight matrices to bf16 (Wq,Wk,Wv,Wo,W1,W2 concatenated).
__global__ __launch_bounds__(256) void prep_kernel(const int* __restrict__ adj,
                                                   unsigned* __restrict__ mask,
                                                   const float* __restrict__ Wq,
                                                   const float* __restrict__ Wk,
                                                   const float* __restrict__ Wv,
                                                   const float* __restrict__ Wo,
                                                   const float* __restrict__ W1,
                                                   const float* __restrict__ W2,
                                                   short* __restrict__ wout) {
    if (blockIdx.x < 65536) {
        const int gw   = (blockIdx.x * 256 + threadIdx.x) >> 6;
        const int lane = threadIdx.x & 63;
        const int row  = gw >> 6;
        const int chunk = gw & 63;
        const int c = chunk * 64 + lane;
        int a = adj[(size_t)row * NROWS + c];
        unsigned long long m = __ballot(a > 0 || c == row);
        if (lane == 0)      mask[row * 128 + chunk * 2]     = (unsigned)m;
        else if (lane == 1) mask[row * 128 + chunk * 2 + 1] = (unsigned)(m >> 32);
    } else {
        int i = ((blockIdx.x - 65536) * 256 + threadIdx.x) * 8;  // 524288 floats
        const float* src; int off;
        if (i < 262144) {
            const float* ws[4] = {Wq, Wk, Wv, Wo};
            src = ws[i >> 16]; off = i & 65535;
        } else if (i < 393216) { src = W1; off = i - 262144; }
        else                   { src = W2; off = i - 393216; }
        float4 a = *(const float4*)(src + off);
        float4 b = *(const float4*)(src + off + 4);
        *(s16x8*)(wout + i) = pack8(a, b);
    }
}

// ---------------------------------------------------------------------------
// QKV projection, wide tiles: wave = 16 rows x 128 cols (8 indep acc chains).
// Q gets scale*log2e folded in. Layouts: Qb[n][d], Kb[h][key][hd], Vtb[h][hd][key].
__global__ __launch_bounds__(256) void qkv_kernel(const float* __restrict__ X,
                                                  const short* __restrict__ Wb,
                                                  const float* __restrict__ bq,
                                                  const float* __restrict__ bk,
                                                  const float* __restrict__ bv,
                                                  short* __restrict__ Qb,
                                                  short* __restrict__ Kb,
                                                  short* __restrict__ Vtb) {
    const int z = blockIdx.z;
    const short* W = Wb + (size_t)z * 65536;
    const float* bias = (z == 0) ? bq : (z == 1 ? bk : bv);
    const int tid = threadIdx.x;
    const int wv = tid >> 6, lane = tid & 63;
    const int quad = lane >> 4, col = lane & 15;
    const int n0 = blockIdx.x * 64 + wv * 16;
    const int o0 = blockIdx.y * 128;
    const float QSC = 0.25505653437397888f;  // log2e / sqrt(32)

    f32x4 zero = {0.f, 0.f, 0.f, 0.f};
    f32x4 acc[8] = {zero, zero, zero, zero, zero, zero, zero, zero};
    const float* ap = X + (size_t)(n0 + col) * DMODEL + quad * 8;
    const short* wp = W + (size_t)(o0 + col) * DMODEL + quad * 8;
#pragma unroll 2
    for (int k0 = 0; k0 < DMODEL; k0 += 32) {
        float4 a0 = *(const float4*)(ap + k0);
        float4 a1 = *(const float4*)(ap + k0 + 4);
        s16x8 af = pack8(a0, a1);
#pragma unroll
        for (int t = 0; t < 8; ++t) {
            s16x8 bf = *(const s16x8*)(wp + (size_t)t * 16 * DMODEL + k0);
            acc[t] = __builtin_amdgcn_mfma_f32_16x16x32_bf16(af, bf, acc[t], 0, 0, 0);
        }
    }
#pragma unroll
    for (int t = 0; t < 8; ++t) {
        const int o = o0 + t * 16 + col;
        float bvv = bias[o];
#pragma unroll
        for (int r = 0; r < 4; ++r) {
            int n = n0 + quad * 4 + r;
            float v = acc[t][r] + bvv;
            if (z == 0)      Qb[(size_t)n * DMODEL + o] = bf16r(v * QSC);
            else if (z == 1) Kb[(size_t)(o >> 5) * NROWS * HDIM + (size_t)n * HDIM + (o & 31)] = bf16r(v);
            else             Vtb[(size_t)o * NROWS + n] = bf16r(v);
        }
    }
}

// ---------------------------------------------------------------------------
// Flash attention, S^T orientation, fixed-M softmax, 32 q per wave (2 subtiles
// sharing K/V fragments), 4-way key split, K+mask double-buffer prefetch,
// sP/sO LDS union (per-wave region, same-wave ordering makes overlap safe).
__global__ __launch_bounds__(256) void attn_kernel(const short* __restrict__ Qb,
                                                   const short* __restrict__ Kb,
                                                   const short* __restrict__ Vtb,
                                                   const unsigned* __restrict__ mask,
                                                   short* __restrict__ Om) {
    __shared__ union {
        short sP[2][16 * PSTRIDE];     // 4608 B (P scratch, during K-loop)
        float sO[HDIM][OSTRIDE];       // 4224 B (merge buffer, after loop)
    } u[4];
    __shared__ float sl[4][32];

    const int tid = threadIdx.x;
    const int wv = tid >> 6, lane = tid & 63;
    const int quad = lane >> 4, col = lane & 15;
    const int h = blockIdx.x & 7;
    const int q0 = (blockIdx.x >> 3) * 32;
    const int kw = wv * 1024;

    s16x8 qf[2];
    qf[0] = *(const s16x8*)(Qb + (size_t)(q0 + col) * DMODEL + h * HDIM + quad * 8);
    qf[1] = *(const s16x8*)(Qb + (size_t)(q0 + 16 + col) * DMODEL + h * HDIM + quad * 8);

    const short* kp  = Kb + (size_t)h * NROWS * HDIM + (size_t)(kw + col) * HDIM + quad * 8;
    const short* vp0 = Vtb + (size_t)(h * HDIM + col) * NROWS + kw + quad * 8;
    const short* vp1 = vp0 + (size_t)16 * NROWS;
    const unsigned* mp0 = mask + (size_t)(q0 + col) * 128 + (kw >> 5);
    const unsigned* mp1 = mp0 + 16 * 128;

    f32x4 zero = {0.f, 0.f, 0.f, 0.f};
    f32x4 acc[2][2] = {{zero, zero}, {zero, zero}};
    float rs[2] = {0.f, 0.f};
    const f32x4 cinit = {-M2C, -M2C, -M2C, -M2C};

    auto loadK = [&](int it, s16x8* kf, uint2* w0, uint2* w1) {
        const short* k = kp + it * 64 * HDIM;
        kf[0] = *(const s16x8*)(k);
        kf[1] = *(const s16x8*)(k + 16 * HDIM);
        kf[2] = *(const s16x8*)(k + 32 * HDIM);
        kf[3] = *(const s16x8*)(k + 48 * HDIM);
        *w0 = *(const uint2*)(mp0 + it * 2);
        *w1 = *(const uint2*)(mp1 + it * 2);
    };

    auto proc = [&](const s16x8* kf, uint2 w0, uint2 w1, int it) {
        const short* v0 = vp0 + it * 64;
        const short* v1 = vp1 + it * 64;
        s16x8 vf00 = *(const s16x8*)(v0);
        s16x8 vf01 = *(const s16x8*)(v0 + 32);
        s16x8 vf10 = *(const s16x8*)(v1);
        s16x8 vf11 = *(const s16x8*)(v1 + 32);
#pragma unroll
        for (int qs = 0; qs < 2; ++qs) {
            unsigned wlo = (qs ? w1.x : w0.x) >> (quad * 4);
            unsigned whi = (qs ? w1.y : w0.y) >> (quad * 4);
            f32x4 st[4];
            st[0] = __builtin_amdgcn_mfma_f32_16x16x32_bf16(kf[0], qf[qs], cinit, 0, 0, 0);
            st[1] = __builtin_amdgcn_mfma_f32_16x16x32_bf16(kf[1], qf[qs], cinit, 0, 0, 0);
            st[2] = __builtin_amdgcn_mfma_f32_16x16x32_bf16(kf[2], qf[qs], cinit, 0, 0, 0);
            st[3] = __builtin_amdgcn_mfma_f32_16x16x32_bf16(kf[3], qf[qs], cinit, 0, 0, 0);

            float p[4][4];
            float r0 = 0.f;
#pragma unroll
            for (int t = 0; t < 4; ++t) {
                unsigned wm = (t < 2) ? wlo : whi;
#pragma unroll
                for (int r = 0; r < 4; ++r) {
                    float e = fexp2(st[t][r]);
                    bool ok = (wm & (1u << ((t & 1) * 16 + r))) != 0u;
                    p[t][r] = ok ? e : 0.f;
                    r0 += p[t][r];
                }
            }
            rs[qs] += r0;

            short* pb = &u[wv].sP[qs][0];
#pragma unroll
            for (int t = 0; t < 4; ++t) {
                uint2 pr;
                pr.x = pk_bf16(p[t][0], p[t][1]);
                pr.y = pk_bf16(p[t][2], p[t][3]);
                *(uint2*)(pb + col * PSTRIDE + t * 16 + quad * 4) = pr;
            }
            s16x8 pb0 = *(const s16x8*)(pb + col * PSTRIDE + quad * 8);
            s16x8 pb1 = *(const s16x8*)(pb + col * PSTRIDE + 32 + quad * 8);

            acc[qs][0] = __builtin_amdgcn_mfma_f32_16x16x32_bf16(vf00, pb0, acc[qs][0], 0, 0, 0);
            acc[qs][0] = __builtin_amdgcn_mfma_f32_16x16x32_bf16(vf01, pb1, acc[qs][0], 0, 0, 0);
            acc[qs][1] = __builtin_amdgcn_mfma_f32_16x16x32_bf16(vf10, pb0, acc[qs][1], 0, 0, 0);
            acc[qs][1] = __builtin_amdgcn_mfma_f32_16x16x32_bf16(vf11, pb1, acc[qs][1], 0, 0, 0);
        }
    };

    s16x8 kfA[4], kfB[4];
    uint2 w0A, w1A, w0B, w1B;
    loadK(0, kfA, &w0A, &w1A);
    for (int it = 0; it < 16; it += 2) {
        loadK(it + 1, kfB, &w0B, &w1B);
        proc(kfA, w0A, w1A, it);
        if (it < 14) loadK(it + 2, kfA, &w0A, &w1A);
        proc(kfB, w0B, w1B, it + 1);
    }

    // partition partials -> LDS (sP region of this wave is dead now)
#pragma unroll
    for (int qs = 0; qs < 2; ++qs) {
        float r = rs[qs];
        r += __shfl_xor(r, 16, 64);
        r += __shfl_xor(r, 32, 64);
        if (lane < 16) sl[wv][qs * 16 + col] = r;
#pragma unroll
        for (int rr = 0; rr < 4; ++rr) {
            u[wv].sO[quad * 4 + rr][qs * 16 + col]      = acc[qs][0][rr];
            u[wv].sO[16 + quad * 4 + rr][qs * 16 + col] = acc[qs][1][rr];
        }
    }
    __syncthreads();

    // merge 4 key-partitions: thread -> (q = tid>>3 in 0..31, 4 hd)
    const int q = tid >> 3, hd0 = (tid & 7) * 4;
    float l = sl[0][q] + sl[1][q] + sl[2][q] + sl[3][q];
    float inv = 1.f / l;  // diagonal always allowed -> l > 0
    float o[4];
#pragma unroll
    for (int j = 0; j < 4; ++j) {
        int hd = hd0 + j;
        o[j] = (u[0].sO[hd][q] + u[1].sO[hd][q] + u[2].sO[hd][q] + u[3].sO[hd][q]) * inv;
    }
    uint2 ob;
    ob.x = pk_bf16(o[0], o[1]);
    ob.y = pk_bf16(o[2], o[3]);
    *(uint2*)(Om + (size_t)(q0 + q) * DMODEL + h * HDIM + hd0) = ob;
}

// ---------------------------------------------------------------------------
// bf16-in GEMM, wide tiles: wave = 16 rows x 128 cols (8 indep acc chains).
template<int K, bool RELU, bool B16OUT>
__global__ __launch_bounds__(256) void gemm_t(const short* __restrict__ A,
                                              const short* __restrict__ W,
                                              const float* __restrict__ bias,
                                              float* __restrict__ Cf,
                                              short* __restrict__ Cb,
                                              int Ocols) {
    const int tid = threadIdx.x;
    const int wv = tid >> 6, lane = tid & 63;
    const int quad = lane >> 4, col = lane & 15;
    const int n0 = blockIdx.x * 64 + wv * 16;
    const int o0 = blockIdx.y * 128;
    f32x4 zero = {0.f, 0.f, 0.f, 0.f};
    f32x4 acc[8] = {zero, zero, zero, zero, zero, zero, zero, zero};
    const short* ap = A + (size_t)(n0 + col) * K + quad * 8;
    const short* wp = W + (size_t)(o0 + col) * K + quad * 8;
#pragma unroll 2
    for (int k0 = 0; k0 < K; k0 += 32) {
        s16x8 af = *(const s16x8*)(ap + k0);
#pragma unroll
        for (int t = 0; t < 8; ++t) {
            s16x8 bf = *(const s16x8*)(wp + (size_t)t * 16 * K + k0);
            acc[t] = __builtin_amdgcn_mfma_f32_16x16x32_bf16(af, bf, acc[t], 0, 0, 0);
        }
    }
#pragma unroll
    for (int t = 0; t < 8; ++t) {
        const int o = o0 + t * 16 + col;
        float bvv = bias[o];
#pragma unroll
        for (int r = 0; r < 4; ++r) {
            int n = n0 + quad * 4 + r;
            float v = acc[t][r] + bvv;
            if (RELU) v = fmaxf(v, 0.f);
            if (B16OUT) Cb[(size_t)n * Ocols + o] = bf16r(v);
            else        Cf[(size_t)n * Ocols + o] = v;
        }
    }
}

// ---------------------------------------------------------------------------
// y = LN(a+b)*g + beta; writes f32 Y and optional bf16 Yb.
__global__ __launch_bounds__(256) void ln_kernel(const float* __restrict__ Xa,
                                                 const float* __restrict__ Xb,
                                                 const float* __restrict__ g,
                                                 const float* __restrict__ be,
                                                 float* __restrict__ Y,
                                                 short* __restrict__ Yb) {
    const int wv = threadIdx.x >> 6, lane = threadIdx.x & 63;
    const int row = blockIdx.x * 4 + wv;
    const float4 av = *(const float4*)(Xa + (size_t)row * DMODEL + lane * 4);
    const float4 bv = *(const float4*)(Xb + (size_t)row * DMODEL + lane * 4);
    float v0 = av.x + bv.x, v1 = av.y + bv.y, v2 = av.z + bv.z, v3 = av.w + bv.w;
    float s = v0 + v1 + v2 + v3;
#pragma unroll
    for (int m = 1; m < 64; m <<= 1) s += __shfl_xor(s, m, 64);
    float mean = s * (1.f / 256.f);
    float d0 = v0 - mean, d1 = v1 - mean, d2 = v2 - mean, d3 = v3 - mean;
    float q = d0 * d0 + d1 * d1 + d2 * d2 + d3 * d3;
#pragma unroll
    for (int m = 1; m < 64; m <<= 1) q += __shfl_xor(q, m, 64);
    float rstd = rsqrtf(q * (1.f / 256.f) + 1e-5f);
    const float4 gv  = *(const float4*)(g + lane * 4);
    const float4 bev = *(const float4*)(be + lane * 4);
    float4 y;
    y.x = d0 * rstd * gv.x + bev.x;
    y.y = d1 * rstd * gv.y + bev.y;
    y.z = d2 * rstd * gv.z + bev.z;
    y.w = d3 * rstd * gv.w + bev.w;
    *(float4*)(Y + (size_t)row * DMODEL + lane * 4) = y;
    if (Yb) {
        uint2 yb;
        yb.x = pk_bf16(y.x, y.y);
        yb.y = pk_bf16(y.z, y.w);
        *(uint2*)(Yb + (size_t)row * DMODEL + lane * 4) = yb;
    }
}

// ---------------------------------------------------------------------------
extern "C" void kernel_launch(void* const* d_in, const int* in_sizes, int n_in,
                              void* d_out, int out_size, void* d_ws, size_t ws_size,
                              hipStream_t stream) {
    const float* x   = (const float*)d_in[0];
    const int*   adj = (const int*)d_in[1];
    const float* Wq  = (const float*)d_in[2];
    const float* Wk  = (const float*)d_in[3];
    const float* Wv  = (const float*)d_in[4];
    const float* bq  = (const float*)d_in[5];
    const float* bk  = (const float*)d_in[6];
    const float* bv  = (const float*)d_in[7];
    const float* Wo  = (const float*)d_in[8];
    const float* bo  = (const float*)d_in[9];
    const float* g1  = (const float*)d_in[10];
    const float* be1 = (const float*)d_in[11];
    const float* W1  = (const float*)d_in[12];
    const float* b1  = (const float*)d_in[13];
    const float* W2  = (const float*)d_in[14];
    const float* b2  = (const float*)d_in[15];
    const float* g2  = (const float*)d_in[16];
    const float* be2 = (const float*)d_in[17];
    float* out = (float*)d_out;

    const size_t NM = (size_t)NROWS * DMODEL;
    char* p = (char*)d_ws;
    unsigned* mask = (unsigned*)p; p += (size_t)NROWS * 128 * 4;  // 2 MB
    short* Wb   = (short*)p;       p += (size_t)524288 * 2;       // 1 MB
    short* Qb   = (short*)p;       p += NM * 2;                   // 2 MB
    short* Kb   = (short*)p;       p += NM * 2;                   // 2 MB
    short* Vtb  = (short*)p;       p += NM * 2;                   // 2 MB
    short* Omb  = (short*)p;       p += NM * 2;                   // 2 MB
    float* hbuf = (float*)p;       p += NM * 4;                   // 4 MB
    float* y1   = (float*)p;       p += NM * 4;                   // 4 MB
    short* y1b  = (short*)p;       p += NM * 2;                   // 2 MB
    short* rbuf = (short*)p;       p += (size_t)NROWS * 512 * 2;  // 4 MB
    float* t2   = (float*)p;       p += NM * 4;                   // 4 MB

    prep_kernel<<<dim3(65792), dim3(256), 0, stream>>>(adj, mask, Wq, Wk, Wv, Wo, W1, W2, Wb);
    qkv_kernel<<<dim3(64, 2, 3), dim3(256), 0, stream>>>(x, Wb, bq, bk, bv, Qb, Kb, Vtb);
    attn_kernel<<<dim3(1024), dim3(256), 0, stream>>>(Qb, Kb, Vtb, mask, Omb);
    gemm_t<256, false, false><<<dim3(64, 2), dim3(256), 0, stream>>>(Omb, Wb + 196608, bo, hbuf, nullptr, 256);
    ln_kernel<<<dim3(1024), dim3(256), 0, stream>>>(x, hbuf, g1, be1, y1, y1b);
    gemm_t<256, true, true><<<dim3(64, 4), dim3(256), 0, stream>>>(y1b, Wb + 262144, b1, nullptr, rbuf, 512);
    gemm_t<512, false, false><<<dim3(64, 2), dim3(256), 0, stream>>>(rbuf, Wb + 393216, b2, t2, nullptr, 256);
    ln_kernel<<<dim3(1024), dim3(256), 0, stream>>>(y1, t2, g2, be2, out, nullptr);
}

// Round 6
// 261.087 us; speedup vs baseline: 1.2830x; 1.1455x over previous
//
#include <hip/hip_runtime.h>
#include <hip/hip_bf16.h>

typedef __attribute__((ext_vector_type(4))) float f32x4;
typedef __attribute__((ext_vector_type(8))) short s16x8;

#define NROWS 4096
#define DMODEL 256
#define NHEAD 8
#define HDIM 32
#define PSTRIDE 72     // halfwords per P-scratch row: 144 B, 16B-aligned
#define OSTRIDE 33     // f32 per sO row (32 q + 1 pad)
#define M2C 24.0f      // fixed softmax max (log2 domain)
#define NM (NROWS * DMODEL)

__device__ __forceinline__ short bf16r(float f) {
    union { float f; unsigned u; } v; v.f = f;
    unsigned r = v.u + 0x7fffu + ((v.u >> 16) & 1u);  // RNE
    return (short)(r >> 16);
}

__device__ __forceinline__ float fexp2(float x) {
    float r;
    asm("v_exp_f32 %0, %1" : "=v"(r) : "v"(x));
    return r;
}

__device__ __forceinline__ unsigned pk_bf16(float a, float b) {
#if __has_builtin(__builtin_amdgcn_cvt_pk_bf16_f32)
    typedef __bf16 bf2 __attribute__((ext_vector_type(2)));
    union { bf2 h; unsigned u; } c;
    c.h = __builtin_amdgcn_cvt_pk_bf16_f32(a, b);
    return c.u;
#else
    return (unsigned)(unsigned short)bf16r(a) | ((unsigned)(unsigned short)bf16r(b) << 16);
#endif
}

__device__ __forceinline__ s16x8 pack8(float4 a, float4 b) {
    s16x8 r;
    r[0] = bf16r(a.x); r[1] = bf16r(a.y); r[2] = bf16r(a.z); r[3] = bf16r(a.w);
    r[4] = bf16r(b.x); r[5] = bf16r(b.y); r[6] = bf16r(b.z); r[7] = bf16r(b.w);
    return r;
}

// ---------------------------------------------------------------------------
// Fat prep: blocks [0,2048): adj -> bitmask (diag OR'd), 32 wave-tasks each.
// Blocks [2048,2304): pack 6 weight matrices to bf16 (Wq,Wk,Wv,Wo,W1,W2).
__global__ __launch_bounds__(256) void prep_kernel(const int* __restrict__ adj,
                                                   unsigned* __restrict__ mask,
                                                   const float* __restrict__ Wq,
                                                   const float* __restrict__ Wk,
                                                   const float* __restrict__ Wv,
                                                   const float* __restrict__ Wo,
                                                   const float* __restrict__ W1,
                                                   const float* __restrict__ W2,
                                                   short* __restrict__ wout) {
    const int lane = threadIdx.x & 63;
    if (blockIdx.x < 2048) {
        const int waveid = blockIdx.x * 4 + (threadIdx.x >> 6);  // 0..8191
#pragma unroll
        for (int i = 0; i < 32; ++i) {
            const int task = waveid + i * 8192;       // 0..262143 (row,chunk)
            const int row = task >> 6, chunk = task & 63;
            const int c = chunk * 64 + lane;
            int a = adj[(size_t)row * NROWS + c];
            unsigned long long m = __ballot(a > 0 || c == row);
            if (lane == 0)      mask[row * 128 + chunk * 2]     = (unsigned)m;
            else if (lane == 1) mask[row * 128 + chunk * 2 + 1] = (unsigned)(m >> 32);
        }
    } else {
        int i = ((blockIdx.x - 2048) * 256 + threadIdx.x) * 8;  // 524288 floats
        const float* src; int off;
        if (i < 262144) {
            const float* ws[4] = {Wq, Wk, Wv, Wo};
            src = ws[i >> 16]; off = i & 65535;
        } else if (i < 393216) { src = W1; off = i - 262144; }
        else                   { src = W2; off = i - 393216; }
        float4 a = *(const float4*)(src + off);
        float4 b = *(const float4*)(src + off + 4);
        *(s16x8*)(wout + i) = pack8(a, b);
    }
}

// ---------------------------------------------------------------------------
// QKV projection as one GEMM over stacked [Wq;Wk;Wv] (768 rows of Wb).
// Wave = 16 rows x 64 cols (4 chains). Q gets scale*log2e folded in.
// Layouts: Qb[n][d], Kb[h][key][hd], Vtb[h][hd][key].
__global__ __launch_bounds__(256) void qkv_kernel(const float* __restrict__ X,
                                                  const short* __restrict__ Wb,
                                                  const float* __restrict__ bq,
                                                  const float* __restrict__ bk,
                                                  const float* __restrict__ bv,
                                                  short* __restrict__ Qb,
                                                  short* __restrict__ Kb,
                                                  short* __restrict__ Vtb) {
    const int tid = threadIdx.x;
    const int wv = tid >> 6, lane = tid & 63;
    const int quad = lane >> 4, col = lane & 15;
    const int n0 = blockIdx.x * 64 + wv * 16;
    const int o0 = blockIdx.y * 64;                 // 0..704, z uniform per block
    const int z = o0 >> 8;
    const float* bias = (z == 0) ? bq : (z == 1 ? bk : bv);
    const float QSC = 0.25505653437397888f;         // log2e / sqrt(32)

    f32x4 zero = {0.f, 0.f, 0.f, 0.f};
    f32x4 acc[4] = {zero, zero, zero, zero};
    const float* ap = X + (size_t)(n0 + col) * DMODEL + quad * 8;
    const short* wp = Wb + (size_t)(o0 + col) * DMODEL + quad * 8;
#pragma unroll
    for (int k0 = 0; k0 < DMODEL; k0 += 32) {
        float4 a0 = *(const float4*)(ap + k0);
        float4 a1 = *(const float4*)(ap + k0 + 4);
        s16x8 af = pack8(a0, a1);
#pragma unroll
        for (int t = 0; t < 4; ++t) {
            s16x8 bf = *(const s16x8*)(wp + (size_t)t * 16 * DMODEL + k0);
            acc[t] = __builtin_amdgcn_mfma_f32_16x16x32_bf16(af, bf, acc[t], 0, 0, 0);
        }
    }
#pragma unroll
    for (int t = 0; t < 4; ++t) {
        const int o = o0 + t * 16 + col;
        const int oo = o & 255;
        float bvv = bias[oo];
#pragma unroll
        for (int r = 0; r < 4; ++r) {
            int n = n0 + quad * 4 + r;
            float v = acc[t][r] + bvv;
            if (z == 0)      Qb[(size_t)n * DMODEL + oo] = bf16r(v * QSC);
            else if (z == 1) Kb[(size_t)(oo >> 5) * NROWS * HDIM + (size_t)n * HDIM + (oo & 31)] = bf16r(v);
            else             Vtb[(size_t)oo * NROWS + n] = bf16r(v);
        }
    }
}

// ---------------------------------------------------------------------------
// Flash attention, S^T orientation, fixed-M softmax, 32 q per wave (2 q-subtiles
// sharing K/V fragments), 8-way key split (2 key-half blocks x 4 waves).
// Row-sums l computed on the MFMA pipe via ones-row A-fragment (P·1).
// Outputs PARTIAL sums (fixed M -> linear): Opart[khalf], lpart[khalf].
__global__ __launch_bounds__(256) void attn_kernel(const short* __restrict__ Qb,
                                                   const short* __restrict__ Kb,
                                                   const short* __restrict__ Vtb,
                                                   const unsigned* __restrict__ mask,
                                                   float* __restrict__ Opart,
                                                   float* __restrict__ lpart) {
    __shared__ union {
        short sP[2][16 * PSTRIDE];     // 4608 B (P scratch, during K-loop)
        float sO[HDIM][OSTRIDE];       // 4224 B (merge buffer, after loop)
    } u[4];
    __shared__ float sl[4][32];

    const int tid = threadIdx.x;
    const int wv = tid >> 6, lane = tid & 63;
    const int quad = lane >> 4, col = lane & 15;
    const int khalf = blockIdx.x & 1;
    const int h = (blockIdx.x >> 1) & 7;
    const int q0 = (blockIdx.x >> 4) * 32;
    const int kw = khalf * 2048 + wv * 512;

    s16x8 qf[2];
    qf[0] = *(const s16x8*)(Qb + (size_t)(q0 + col) * DMODEL + h * HDIM + quad * 8);
    qf[1] = *(const s16x8*)(Qb + (size_t)(q0 + 16 + col) * DMODEL + h * HDIM + quad * 8);

    const short* kp  = Kb + (size_t)h * NROWS * HDIM + (size_t)(kw + col) * HDIM + quad * 8;
    const short* vp0 = Vtb + (size_t)(h * HDIM + col) * NROWS + kw + quad * 8;
    const short* vp1 = vp0 + (size_t)16 * NROWS;
    const unsigned* mp0 = mask + (size_t)(q0 + col) * 128 + (kw >> 5);
    const unsigned* mp1 = mp0 + 16 * 128;

    // ones-row A fragment: A[m=lane&15][k] = (m==0) ? 1.0bf : 0
    const short onev = (col == 0) ? (short)0x3F80 : (short)0;
    const s16x8 ones = {onev, onev, onev, onev, onev, onev, onev, onev};

    f32x4 zero = {0.f, 0.f, 0.f, 0.f};
    f32x4 acc[2][2] = {{zero, zero}, {zero, zero}};
    f32x4 lacc[2] = {zero, zero};
    const f32x4 cinit = {-M2C, -M2C, -M2C, -M2C};

    auto loadK = [&](int it, s16x8* kf, uint2* w0, uint2* w1) {
        const short* k = kp + it * 64 * HDIM;
        kf[0] = *(const s16x8*)(k);
        kf[1] = *(const s16x8*)(k + 16 * HDIM);
        kf[2] = *(const s16x8*)(k + 32 * HDIM);
        kf[3] = *(const s16x8*)(k + 48 * HDIM);
        *w0 = *(const uint2*)(mp0 + it * 2);
        *w1 = *(const uint2*)(mp1 + it * 2);
    };

    auto proc = [&](const s16x8* kf, uint2 w0, uint2 w1, int it) {
        const short* v0 = vp0 + it * 64;
        const short* v1 = vp1 + it * 64;
        s16x8 vf00 = *(const s16x8*)(v0);
        s16x8 vf01 = *(const s16x8*)(v0 + 32);
        s16x8 vf10 = *(const s16x8*)(v1);
        s16x8 vf11 = *(const s16x8*)(v1 + 32);
#pragma unroll
        for (int qs = 0; qs < 2; ++qs) {
            unsigned wlo = (qs ? w1.x : w0.x) >> (quad * 4);
            unsigned whi = (qs ? w1.y : w0.y) >> (quad * 4);
            f32x4 st[4];
            st[0] = __builtin_amdgcn_mfma_f32_16x16x32_bf16(kf[0], qf[qs], cinit, 0, 0, 0);
            st[1] = __builtin_amdgcn_mfma_f32_16x16x32_bf16(kf[1], qf[qs], cinit, 0, 0, 0);
            st[2] = __builtin_amdgcn_mfma_f32_16x16x32_bf16(kf[2], qf[qs], cinit, 0, 0, 0);
            st[3] = __builtin_amdgcn_mfma_f32_16x16x32_bf16(kf[3], qf[qs], cinit, 0, 0, 0);

            float p[4][4];
#pragma unroll
            for (int t = 0; t < 4; ++t) {
                unsigned wm = (t < 2) ? wlo : whi;
#pragma unroll
                for (int r = 0; r < 4; ++r) {
                    float e = fexp2(st[t][r]);
                    bool ok = (wm & (1u << ((t & 1) * 16 + r))) != 0u;
                    p[t][r] = ok ? e : 0.f;
                }
            }

            short* pb = &u[wv].sP[qs][0];
#pragma unroll
            for (int t = 0; t < 4; ++t) {
                uint2 pr;
                pr.x = pk_bf16(p[t][0], p[t][1]);
                pr.y = pk_bf16(p[t][2], p[t][3]);
                *(uint2*)(pb + col * PSTRIDE + t * 16 + quad * 4) = pr;
            }
            s16x8 pb0 = *(const s16x8*)(pb + col * PSTRIDE + quad * 8);
            s16x8 pb1 = *(const s16x8*)(pb + col * PSTRIDE + 32 + quad * 8);

            acc[qs][0] = __builtin_amdgcn_mfma_f32_16x16x32_bf16(vf00, pb0, acc[qs][0], 0, 0, 0);
            acc[qs][0] = __builtin_amdgcn_mfma_f32_16x16x32_bf16(vf01, pb1, acc[qs][0], 0, 0, 0);
            acc[qs][1] = __builtin_amdgcn_mfma_f32_16x16x32_bf16(vf10, pb0, acc[qs][1], 0, 0, 0);
            acc[qs][1] = __builtin_amdgcn_mfma_f32_16x16x32_bf16(vf11, pb1, acc[qs][1], 0, 0, 0);
            // row-sums on the MFMA pipe: lacc row 0 += P·1
            lacc[qs] = __builtin_amdgcn_mfma_f32_16x16x32_bf16(ones, pb0, lacc[qs], 0, 0, 0);
            lacc[qs] = __builtin_amdgcn_mfma_f32_16x16x32_bf16(ones, pb1, lacc[qs], 0, 0, 0);
        }
    };

    s16x8 kfA[4], kfB[4];
    uint2 w0A, w1A, w0B, w1B;
    loadK(0, kfA, &w0A, &w1A);
    for (int it = 0; it < 8; it += 2) {
        loadK(it + 1, kfB, &w0B, &w1B);
        proc(kfA, w0A, w1A, it);
        if (it < 6) loadK(it + 2, kfA, &w0A, &w1A);
        proc(kfB, w0B, w1B, it + 1);
    }

    // partition partials -> LDS (sP region of this wave is dead now)
#pragma unroll
    for (int qs = 0; qs < 2; ++qs) {
        if (lane < 16) sl[wv][qs * 16 + col] = lacc[qs][0];  // D row 0
#pragma unroll
        for (int rr = 0; rr < 4; ++rr) {
            u[wv].sO[quad * 4 + rr][qs * 16 + col]      = acc[qs][0][rr];
            u[wv].sO[16 + quad * 4 + rr][qs * 16 + col] = acc[qs][1][rr];
        }
    }
    __syncthreads();

    // merge this block's 4 key-partitions; write PARTIAL sums for this khalf
    const int q = tid >> 3, hd0 = (tid & 7) * 4;
    float l = sl[0][q] + sl[1][q] + sl[2][q] + sl[3][q];
    float4 ov;
    ov.x = u[0].sO[hd0][q]     + u[1].sO[hd0][q]     + u[2].sO[hd0][q]     + u[3].sO[hd0][q];
    ov.y = u[0].sO[hd0 + 1][q] + u[1].sO[hd0 + 1][q] + u[2].sO[hd0 + 1][q] + u[3].sO[hd0 + 1][q];
    ov.z = u[0].sO[hd0 + 2][q] + u[1].sO[hd0 + 2][q] + u[2].sO[hd0 + 2][q] + u[3].sO[hd0 + 2][q];
    ov.w = u[0].sO[hd0 + 3][q] + u[1].sO[hd0 + 3][q] + u[2].sO[hd0 + 3][q] + u[3].sO[hd0 + 3][q];
    *(float4*)(Opart + (size_t)khalf * NM + (size_t)(q0 + q) * DMODEL + h * HDIM + hd0) = ov;
    if ((tid & 7) == 0) lpart[khalf * NROWS * NHEAD + (q0 + q) * NHEAD + h] = l;
}

// ---------------------------------------------------------------------------
// shared GEMM body: wave = 16 rows x 64 cols (4 chains), bf16 A/W, f32 acc.
template<int K, bool RELU, bool B16OUT>
__device__ __forceinline__ void gemm_body(const short* __restrict__ A,
                                          const short* __restrict__ W,
                                          const float* __restrict__ bias,
                                          float* __restrict__ Cf,
                                          short* __restrict__ Cb,
                                          int Ocols) {
    const int tid = threadIdx.x;
    const int wv = tid >> 6, lane = tid & 63;
    const int quad = lane >> 4, col = lane & 15;
    const int n0 = blockIdx.x * 64 + wv * 16;
    const int o0 = blockIdx.y * 64;
    f32x4 zero = {0.f, 0.f, 0.f, 0.f};
    f32x4 acc[4] = {zero, zero, zero, zero};
    const short* ap = A + (size_t)(n0 + col) * K + quad * 8;
    const short* wp = W + (size_t)(o0 + col) * K + quad * 8;
#pragma unroll
    for (int k0 = 0; k0 < K; k0 += 32) {
        s16x8 af = *(const s16x8*)(ap + k0);
#pragma unroll
        for (int t = 0; t < 4; ++t) {
            s16x8 bf = *(const s16x8*)(wp + (size_t)t * 16 * K + k0);
            acc[t] = __builtin_amdgcn_mfma_f32_16x16x32_bf16(af, bf, acc[t], 0, 0, 0);
        }
    }
#pragma unroll
    for (int t = 0; t < 4; ++t) {
        const int o = o0 + t * 16 + col;
        float bvv = bias[o];
#pragma unroll
        for (int r = 0; r < 4; ++r) {
            int n = n0 + quad * 4 + r;
            float v = acc[t][r] + bvv;
            if (RELU) v = fmaxf(v, 0.f);
            if (B16OUT) Cb[(size_t)n * Ocols + o] = bf16r(v);
            else        Cf[(size_t)n * Ocols + o] = v;
        }
    }
}

__global__ __launch_bounds__(256) void gemm_w1(const short* __restrict__ A,
                                               const short* __restrict__ W,
                                               const float* __restrict__ bias,
                                               short* __restrict__ Cb) {
    gemm_body<256, true, true>(A, W, bias, nullptr, Cb, 512);
}

__global__ __launch_bounds__(256) void gemm_w2(const short* __restrict__ A,
                                               const short* __restrict__ W,
                                               const float* __restrict__ bias,
                                               float* __restrict__ Cf) {
    gemm_body<512, false, false>(A, W, bias, Cf, nullptr, 256);
}

// ---------------------------------------------------------------------------
// Wo GEMM with fused attention-partial merge + 1/l normalization in A-prep.
__global__ __launch_bounds__(256) void gemm_wo(const float* __restrict__ Opart,
                                               const float* __restrict__ lpart,
                                               const short* __restrict__ W,
                                               const float* __restrict__ bias,
                                               float* __restrict__ Cf) {
    const int tid = threadIdx.x;
    const int wv = tid >> 6, lane = tid & 63;
    const int quad = lane >> 4, col = lane & 15;
    const int n0 = blockIdx.x * 64 + wv * 16;
    const int o0 = blockIdx.y * 64;
    f32x4 zero = {0.f, 0.f, 0.f, 0.f};
    f32x4 acc[4] = {zero, zero, zero, zero};
    const int n = n0 + col;
    const float* a0p = Opart + (size_t)n * DMODEL + quad * 8;
    const float* a1p = a0p + NM;
    const float* l0p = lpart + (size_t)n * NHEAD;
    const float* l1p = l0p + NROWS * NHEAD;
    const short* wp = W + (size_t)(o0 + col) * DMODEL + quad * 8;
#pragma unroll
    for (int k0 = 0; k0 < DMODEL; k0 += 32) {
        const int head = k0 >> 5;
        float inv = 1.f / (l0p[head] + l1p[head]);   // diag allowed -> l > 0
        float4 xa = *(const float4*)(a0p + k0);
        float4 xb = *(const float4*)(a0p + k0 + 4);
        float4 ya = *(const float4*)(a1p + k0);
        float4 yb = *(const float4*)(a1p + k0 + 4);
        float4 s0, s1;
        s0.x = (xa.x + ya.x) * inv; s0.y = (xa.y + ya.y) * inv;
        s0.z = (xa.z + ya.z) * inv; s0.w = (xa.w + ya.w) * inv;
        s1.x = (xb.x + yb.x) * inv; s1.y = (xb.y + yb.y) * inv;
        s1.z = (xb.z + yb.z) * inv; s1.w = (xb.w + yb.w) * inv;
        s16x8 af = pack8(s0, s1);
#pragma unroll
        for (int t = 0; t < 4; ++t) {
            s16x8 bf = *(const s16x8*)(wp + (size_t)t * 16 * DMODEL + k0);
            acc[t] = __builtin_amdgcn_mfma_f32_16x16x32_bf16(af, bf, acc[t], 0, 0, 0);
        }
    }
#pragma unroll
    for (int t = 0; t < 4; ++t) {
        const int o = o0 + t * 16 + col;
        float bvv = bias[o];
#pragma unroll
        for (int r = 0; r < 4; ++r)
            Cf[(size_t)(n0 + quad * 4 + r) * DMODEL + o] = acc[t][r] + bvv;
    }
}

// ---------------------------------------------------------------------------
// y = LN(a+b)*g + beta; writes f32 Y and optional bf16 Yb.
__global__ __launch_bounds__(256) void ln_kernel(const float* __restrict__ Xa,
                                                 const float* __restrict__ Xb,
                                                 const float* __restrict__ g,
                                                 const float* __restrict__ be,
                                                 float* __restrict__ Y,
                                                 short* __restrict__ Yb) {
    const int wv = threadIdx.x >> 6, lane = threadIdx.x & 63;
    const int row = blockIdx.x * 4 + wv;
    const float4 av = *(const float4*)(Xa + (size_t)row * DMODEL + lane * 4);
    const float4 bv = *(const float4*)(Xb + (size_t)row * DMODEL + lane * 4);
    float v0 = av.x + bv.x, v1 = av.y + bv.y, v2 = av.z + bv.z, v3 = av.w + bv.w;
    float s = v0 + v1 + v2 + v3;
#pragma unroll
    for (int m = 1; m < 64; m <<= 1) s += __shfl_xor(s, m, 64);
    float mean = s * (1.f / 256.f);
    float d0 = v0 - mean, d1 = v1 - mean, d2 = v2 - mean, d3 = v3 - mean;
    float q = d0 * d0 + d1 * d1 + d2 * d2 + d3 * d3;
#pragma unroll
    for (int m = 1; m < 64; m <<= 1) q += __shfl_xor(q, m, 64);
    float rstd = rsqrtf(q * (1.f / 256.f) + 1e-5f);
    const float4 gv  = *(const float4*)(g + lane * 4);
    const float4 bev = *(const float4*)(be + lane * 4);
    float4 y;
    y.x = d0 * rstd * gv.x + bev.x;
    y.y = d1 * rstd * gv.y + bev.y;
    y.z = d2 * rstd * gv.z + bev.z;
    y.w = d3 * rstd * gv.w + bev.w;
    *(float4*)(Y + (size_t)row * DMODEL + lane * 4) = y;
    if (Yb) {
        uint2 yb;
        yb.x = pk_bf16(y.x, y.y);
        yb.y = pk_bf16(y.z, y.w);
        *(uint2*)(Yb + (size_t)row * DMODEL + lane * 4) = yb;
    }
}

// ---------------------------------------------------------------------------
extern "C" void kernel_launch(void* const* d_in, const int* in_sizes, int n_in,
                              void* d_out, int out_size, void* d_ws, size_t ws_size,
                              hipStream_t stream) {
    const float* x   = (const float*)d_in[0];
    const int*   adj = (const int*)d_in[1];
    const float* Wq  = (const float*)d_in[2];
    const float* Wk  = (const float*)d_in[3];
    const float* Wv  = (const float*)d_in[4];
    const float* bq  = (const float*)d_in[5];
    const float* bk  = (const float*)d_in[6];
    const float* bv  = (const float*)d_in[7];
    const float* Wo  = (const float*)d_in[8];
    const float* bo  = (const float*)d_in[9];
    const float* g1  = (const float*)d_in[10];
    const float* be1 = (const float*)d_in[11];
    const float* W1  = (const float*)d_in[12];
    const float* b1  = (const float*)d_in[13];
    const float* W2  = (const float*)d_in[14];
    const float* b2  = (const float*)d_in[15];
    const float* g2  = (const float*)d_in[16];
    const float* be2 = (const float*)d_in[17];
    float* out = (float*)d_out;

    char* p = (char*)d_ws;
    unsigned* mask = (unsigned*)p; p += (size_t)NROWS * 128 * 4;          //  2 MB
    short* Wb    = (short*)p;      p += (size_t)524288 * 2;               //  1 MB
    short* Qb    = (short*)p;      p += (size_t)NM * 2;                   //  2 MB
    short* Kb    = (short*)p;      p += (size_t)NM * 2;                   //  2 MB
    short* Vtb   = (short*)p;      p += (size_t)NM * 2;                   //  2 MB
    float* Opart = (float*)p;      p += (size_t)2 * NM * 4;               //  8 MB
    float* lpart = (float*)p;      p += (size_t)2 * NROWS * NHEAD * 4;    // .25 MB
    float* hbuf  = (float*)p;      p += (size_t)NM * 4;                   //  4 MB
    float* y1    = (float*)p;      p += (size_t)NM * 4;                   //  4 MB
    short* y1b   = (short*)p;      p += (size_t)NM * 2;                   //  2 MB
    short* rbuf  = (short*)p;      p += (size_t)NROWS * 512 * 2;          //  4 MB
    float* t2    = Opart;          // alias: Opart dead after gemm_wo

    prep_kernel<<<dim3(2304), dim3(256), 0, stream>>>(adj, mask, Wq, Wk, Wv, Wo, W1, W2, Wb);
    qkv_kernel<<<dim3(64, 12), dim3(256), 0, stream>>>(x, Wb, bq, bk, bv, Qb, Kb, Vtb);
    attn_kernel<<<dim3(2048), dim3(256), 0, stream>>>(Qb, Kb, Vtb, mask, Opart, lpart);
    gemm_wo<<<dim3(64, 4), dim3(256), 0, stream>>>(Opart, lpart, Wb + 196608, bo, hbuf);
    ln_kernel<<<dim3(1024), dim3(256), 0, stream>>>(x, hbuf, g1, be1, y1, y1b);
    gemm_w1<<<dim3(64, 8), dim3(256), 0, stream>>>(y1b, Wb + 262144, b1, rbuf);
    gemm_w2<<<dim3(64, 4), dim3(256), 0, stream>>>(rbuf, Wb + 393216, b2, t2);
    ln_kernel<<<dim3(1024), dim3(256), 0, stream>>>(y1, t2, g2, be2, out, nullptr);
}